// Round 4
// baseline (838.336 us; speedup 1.0000x reference)
//
#include <hip/hip_runtime.h>

#define DIM 64

// ---------------------------------------------------------------------------
// LightGCN: 3 x (y[row] += val * x[col]) over COO edges (NNZ=3.2M, N=100k).
//
// Plan A (~52 MB ws): concat embeddings into x_mid (2 d2d copies), build CSR
//   on-device (hist -> 2-level scan -> cursor scatter into interleaved
//   (col,val) 8B records), then 3 x SpMM wave-per-row:
//     - 64 edge records loaded lane-parallel (1 VMEM per 64 edges, nontemporal)
//     - per-edge broadcast to SGPR via __builtin_amdgcn_readlane
//       -> gather uses scalar base address, FMA uses SGPR val operand
//     - coalesced 256B gather per edge, ONE coalesced 256B store per row
//   Zero float atomics; ~1.03 VMEM instr/edge (TA no longer co-limits).
// Plan B (fallback, ~26 MB ws): per-edge f32 atomic scatter.
// Host picks based on ws_size (constant per call -> graph-capture safe).
// ---------------------------------------------------------------------------

#define SCAN_ELEMS 2048      // elements per scan block (256 thr x 8)

typedef unsigned long long u64;

// ---------------- CSR build ----------------

__global__ __launch_bounds__(256) void k_hist(const int* __restrict__ rows,
                                              int* __restrict__ counts, int nnz)
{
    for (int e = blockIdx.x * blockDim.x + threadIdx.x; e < nnz;
         e += gridDim.x * blockDim.x)
        atomicAdd(counts + rows[e], 1);
}

// Per-block exclusive scan of counts -> rp (local), block total -> blocksums[b].
__global__ __launch_bounds__(256) void k_scan1(const int* __restrict__ counts,
                                               int* __restrict__ rp,
                                               int* __restrict__ blocksums, int n)
{
    __shared__ int lds[256];
    const int t = threadIdx.x, b = blockIdx.x;
    const int base = b * SCAN_ELEMS + t * 8;
    int v[8], s = 0;
#pragma unroll
    for (int k = 0; k < 8; ++k) {
        const int idx = base + k;
        v[k] = (idx < n) ? counts[idx] : 0;
        s += v[k];
    }
    lds[t] = s;
    __syncthreads();
    for (int off = 1; off < 256; off <<= 1) {
        const int val = (t >= off) ? lds[t - off] : 0;
        __syncthreads();
        lds[t] += val;
        __syncthreads();
    }
    const int incl = lds[t];
    if (t == 255) blocksums[b] = incl;
    int run = incl - s;   // exclusive prefix of this thread's chunk
#pragma unroll
    for (int k = 0; k < 8; ++k) {
        const int idx = base + k;
        if (idx < n) rp[idx] = run;
        run += v[k];
    }
}

// Exclusive scan of blocksums (nb <= 64: 100k/2048 = 49 blocks).
__global__ void k_scan2(int* __restrict__ blocksums, int nb)
{
    const int lane = threadIdx.x;   // launched with 64 threads = 1 wave
    const int v = (lane < nb) ? blocksums[lane] : 0;
    int incl = v;
    for (int off = 1; off < 64; off <<= 1) {
        const int t = __shfl_up(incl, off);
        if (lane >= off) incl += t;
    }
    if (lane < nb) blocksums[lane] = incl - v;
}

// Add block offsets; init cursor (aliases counts buffer); write row_ptr[n] = nnz.
__global__ __launch_bounds__(256) void k_scan3(int* __restrict__ rp,
                                               const int* __restrict__ blocksums,
                                               int* __restrict__ cursor, int n, int nnz)
{
    for (int i = blockIdx.x * blockDim.x + threadIdx.x; i < n;
         i += gridDim.x * blockDim.x) {
        const int p = rp[i] + blocksums[i / SCAN_ELEMS];
        rp[i] = p;
        cursor[i] = p;
        if (i == 0) rp[n] = nnz;
    }
}

// Scatter edges into CSR order as interleaved 8B records: low32=col, high32=val.
// Nontemporal store: random 8B writes, read once next layer, don't retain in L2.
__global__ __launch_bounds__(256) void k_scatter(
    const int* __restrict__ rows, const int* __restrict__ cols,
    const float* __restrict__ vals, int* __restrict__ cursor,
    u64* __restrict__ edges, int nnz)
{
    for (int e = blockIdx.x * blockDim.x + threadIdx.x; e < nnz;
         e += gridDim.x * blockDim.x) {
        const int p = atomicAdd(cursor + rows[e], 1);
        const u64 rec = ((u64)(unsigned)__float_as_int(vals[e]) << 32)
                      | (u64)(unsigned)cols[e];
        __builtin_nontemporal_store(rec, edges + p);
    }
}

// ---------------- CSR SpMM: wave per row, lane = dim ----------------
// Edge records enter lane-parallel (1 coalesced 512B VMEM per 64 edges),
// then are broadcast to SGPRs via readlane (uniform loop index -> SGPR lane
// operand). Gather address becomes scalar-base + lane*4; FMA takes the edge
// value as its single SGPR operand. TA sees ~1 instruction per edge (gather).

__global__ __launch_bounds__(256) void k_spmm(
    const float* __restrict__ x, const int* __restrict__ row_ptr,
    const u64* __restrict__ edges, float* __restrict__ y,
    int n, int rows_per_wave)
{
    const int lane = threadIdx.x & 63;
    const int w = (blockIdx.x * blockDim.x + threadIdx.x) >> 6;
    int r0 = w * rows_per_wave, r1 = r0 + rows_per_wave;
    if (r1 > n) r1 = n;
    for (int r = r0; r < r1; ++r) {
        const int start = __builtin_amdgcn_readfirstlane(row_ptr[r]);
        const int end   = __builtin_amdgcn_readfirstlane(row_ptr[r + 1]);
        float a0 = 0.f, a1 = 0.f, a2 = 0.f, a3 = 0.f;
        for (int j0 = start; j0 < end; j0 += 64) {
            const int nn = (end - j0 < 64) ? (end - j0) : 64;      // uniform
            // lanes >= nn re-load edge j0 (same line, harmless, never consumed)
            const u64 rec = __builtin_nontemporal_load(
                edges + j0 + ((lane < nn) ? lane : 0));
            const int lo = (int)(unsigned)(rec & 0xffffffffu);      // col bits
            const int hi = (int)(unsigned)(rec >> 32);              // val bits
            int k = 0;
            for (; k + 4 <= nn; k += 4) {
                const int   c0 = __builtin_amdgcn_readlane(lo, k + 0);
                const float v0 = __int_as_float(__builtin_amdgcn_readlane(hi, k + 0));
                const int   c1 = __builtin_amdgcn_readlane(lo, k + 1);
                const float v1 = __int_as_float(__builtin_amdgcn_readlane(hi, k + 1));
                const int   c2 = __builtin_amdgcn_readlane(lo, k + 2);
                const float v2 = __int_as_float(__builtin_amdgcn_readlane(hi, k + 2));
                const int   c3 = __builtin_amdgcn_readlane(lo, k + 3);
                const float v3 = __int_as_float(__builtin_amdgcn_readlane(hi, k + 3));
                a0 += v0 * x[(size_t)c0 * DIM + lane];
                a1 += v1 * x[(size_t)c1 * DIM + lane];
                a2 += v2 * x[(size_t)c2 * DIM + lane];
                a3 += v3 * x[(size_t)c3 * DIM + lane];
            }
            for (; k < nn; ++k) {
                const int   c = __builtin_amdgcn_readlane(lo, k);
                const float v = __int_as_float(__builtin_amdgcn_readlane(hi, k));
                a0 += v * x[(size_t)c * DIM + lane];
            }
        }
        // normal (cached) store: this row is next layer's gather table
        y[(size_t)r * DIM + lane] = (a0 + a1) + (a2 + a3);
    }
}

// ---------------- Plan B fallback: per-edge atomic scatter ----------------

__global__ __launch_bounds__(256) void lgcn_atomic(
    const float* __restrict__ x, const float* __restrict__ vals,
    const int* __restrict__ rows, const int* __restrict__ cols,
    float* __restrict__ y, int nnz, int edges_per_wave)
{
    const int lane = threadIdx.x & 63;
    const int wid = (blockIdx.x * blockDim.x + threadIdx.x) >> 6;
    int e0 = wid * edges_per_wave, e1 = e0 + edges_per_wave;
    if (e1 > nnz) e1 = nnz;
    for (int e = e0; e < e1; ++e) {
        const int eu = __builtin_amdgcn_readfirstlane(e);
        const float v = vals[eu];
        const float xv = x[(size_t)cols[eu] * DIM + lane];
        unsafeAtomicAdd(y + (size_t)rows[eu] * DIM + lane, v * xv);
    }
}

// ---------------- host ----------------

static inline size_t align256(size_t x) { return (x + 255) & ~(size_t)255; }

extern "C" void kernel_launch(void* const* d_in, const int* in_sizes, int n_in,
                              void* d_out, int out_size, void* d_ws, size_t ws_size,
                              hipStream_t stream)
{
    const float* user_emb = (const float*)d_in[0];
    const float* item_emb = (const float*)d_in[1];
    const float* vals     = (const float*)d_in[2];
    const int*   rows     = (const int*)d_in[3];
    const int*   cols     = (const int*)d_in[4];
    float*       out      = (float*)d_out;

    const int n   = (in_sizes[0] + in_sizes[1]) / DIM;   // n_nodes
    const int nnz = in_sizes[2];

    const size_t u_bytes  = (size_t)in_sizes[0] * sizeof(float);
    const size_t i_bytes  = (size_t)in_sizes[1] * sizeof(float);
    const size_t x_bytes  = (size_t)n * DIM * sizeof(float);
    const size_t e_bytes  = (size_t)nnz * sizeof(u64);   // interleaved (col,val)
    const size_t rp_bytes = align256(((size_t)n + 1) * sizeof(int));

    // ws layout
    size_t off = 0;
    float* x_mid  = (float*)((char*)d_ws + off); off += align256(x_bytes);
    u64*   edges  = (u64*)  ((char*)d_ws + off); off += align256(e_bytes);
    int*   row_ptr= (int*)  ((char*)d_ws + off); off += rp_bytes;
    int*   counts = (int*)  ((char*)d_ws + off); off += rp_bytes;
    int*   bsums  = (int*)  ((char*)d_ws + off); off += 256;
    const size_t need = off;
    int*   cursor = counts;                 // counts dead after scan1 -> alias

    const int blocks = 2048, threads = 256;
    const int nwaves = blocks * (threads / 64);

    // x0 = concat(user_emb, item_emb) -> x_mid (both plans)
    hipMemcpyAsync(x_mid, user_emb, u_bytes, hipMemcpyDeviceToDevice, stream);
    hipMemcpyAsync((char*)x_mid + u_bytes, item_emb, i_bytes,
                   hipMemcpyDeviceToDevice, stream);

    if (ws_size >= need) {
        // ---- Plan A: CSR build + 3 gather-SpMM layers ----
        const int nb = (n + SCAN_ELEMS - 1) / SCAN_ELEMS;   // 49 <= 64
        hipMemsetAsync(counts, 0, (size_t)n * sizeof(int), stream);
        k_hist<<<blocks, threads, 0, stream>>>(rows, counts, nnz);
        k_scan1<<<nb, 256, 0, stream>>>(counts, row_ptr, bsums, n);
        k_scan2<<<1, 64, 0, stream>>>(bsums, nb);
        k_scan3<<<blocks, threads, 0, stream>>>(row_ptr, bsums, cursor, n, nnz);
        k_scatter<<<blocks, threads, 0, stream>>>(rows, cols, vals, cursor,
                                                  edges, nnz);
        const int rpw = (n + nwaves - 1) / nwaves;
        k_spmm<<<blocks, threads, 0, stream>>>(x_mid, row_ptr, edges, out, n, rpw);
        k_spmm<<<blocks, threads, 0, stream>>>(out, row_ptr, edges, x_mid, n, rpw);
        k_spmm<<<blocks, threads, 0, stream>>>(x_mid, row_ptr, edges, out, n, rpw);
    } else {
        // ---- Plan B: atomic scatter (needs only x_mid) ----
        const int epw = (nnz + nwaves - 1) / nwaves;
        hipMemsetAsync(out, 0, x_bytes, stream);
        lgcn_atomic<<<blocks, threads, 0, stream>>>(x_mid, vals, rows, cols, out,
                                                    nnz, epw);
        hipMemsetAsync(x_mid, 0, x_bytes, stream);
        lgcn_atomic<<<blocks, threads, 0, stream>>>(out, vals, rows, cols, x_mid,
                                                    nnz, epw);
        hipMemsetAsync(out, 0, x_bytes, stream);
        lgcn_atomic<<<blocks, threads, 0, stream>>>(x_mid, vals, rows, cols, out,
                                                    nnz, epw);
    }
}

// Round 6
// 666.770 us; speedup vs baseline: 1.2573x; 1.2573x over previous
//
#include <hip/hip_runtime.h>

#define DIM 64

// ---------------------------------------------------------------------------
// LightGCN: 3 x (y[row] += val * x[col]) over COO edges (NNZ=3.2M, N=100k).
//
// Plan A (~65 MB ws): concat embeddings into x_mid (2 d2d copies), build CSR:
//   hist (atomicAdd returns within-row slot -> slot[e]) -> 2-level scan ->
//   atomic-free scatter p = row_ptr[row] + slot[e] with CACHED stores
//   (L2/L3 merge the random 8B writes; nt stores here cost 64B/store HBM
//   write-allocate — measured 200 MB WRITE_SIZE, 267 us, round 4).
//   Then 3 x SpMM wave-per-row: 64 edge records loaded lane-parallel
//   (1 VMEM per 64 edges, nt), broadcast via readlane -> scalar gather base,
//   coalesced 256B gather per edge, ONE coalesced 256B store per row.
// Plan A' (~52 MB ws): same but cursor-atomic scatter (no slot array).
// Plan B  (~26 MB ws): per-edge f32 atomic scatter.
// Host picks by ws_size (constant per call -> graph-capture safe).
// ---------------------------------------------------------------------------

#define SCAN_ELEMS 2048      // elements per scan block (256 thr x 8)

typedef unsigned long long u64;

// ---------------- CSR build ----------------

// counts[row]++ and record each edge's within-row slot (atomicAdd return).
__global__ __launch_bounds__(256) void k_hist_slot(const int* __restrict__ rows,
                                                   int* __restrict__ counts,
                                                   int* __restrict__ slot, int nnz)
{
    for (int e = blockIdx.x * blockDim.x + threadIdx.x; e < nnz;
         e += gridDim.x * blockDim.x) {
        const int r = __builtin_nontemporal_load(rows + e);
        slot[e] = atomicAdd(counts + r, 1);
    }
}

__global__ __launch_bounds__(256) void k_hist(const int* __restrict__ rows,
                                              int* __restrict__ counts, int nnz)
{
    for (int e = blockIdx.x * blockDim.x + threadIdx.x; e < nnz;
         e += gridDim.x * blockDim.x)
        atomicAdd(counts + __builtin_nontemporal_load(rows + e), 1);
}

// Per-block exclusive scan of counts -> rp (local), block total -> blocksums[b].
__global__ __launch_bounds__(256) void k_scan1(const int* __restrict__ counts,
                                               int* __restrict__ rp,
                                               int* __restrict__ blocksums, int n)
{
    __shared__ int lds[256];
    const int t = threadIdx.x, b = blockIdx.x;
    const int base = b * SCAN_ELEMS + t * 8;
    int v[8], s = 0;
#pragma unroll
    for (int k = 0; k < 8; ++k) {
        const int idx = base + k;
        v[k] = (idx < n) ? counts[idx] : 0;
        s += v[k];
    }
    lds[t] = s;
    __syncthreads();
    for (int off = 1; off < 256; off <<= 1) {
        const int val = (t >= off) ? lds[t - off] : 0;
        __syncthreads();
        lds[t] += val;
        __syncthreads();
    }
    const int incl = lds[t];
    if (t == 255) blocksums[b] = incl;
    int run = incl - s;   // exclusive prefix of this thread's chunk
#pragma unroll
    for (int k = 0; k < 8; ++k) {
        const int idx = base + k;
        if (idx < n) rp[idx] = run;
        run += v[k];
    }
}

// Exclusive scan of blocksums (nb <= 64: 100k/2048 = 49 blocks).
__global__ void k_scan2(int* __restrict__ blocksums, int nb)
{
    const int lane = threadIdx.x;   // launched with 64 threads = 1 wave
    const int v = (lane < nb) ? blocksums[lane] : 0;
    int incl = v;
    for (int off = 1; off < 64; off <<= 1) {
        const int t = __shfl_up(incl, off);
        if (lane >= off) incl += t;
    }
    if (lane < nb) blocksums[lane] = incl - v;
}

// Add block offsets; optionally init cursor; write row_ptr[n] = nnz.
__global__ __launch_bounds__(256) void k_scan3(int* __restrict__ rp,
                                               const int* __restrict__ blocksums,
                                               int* __restrict__ cursor,  // may be null
                                               int n, int nnz)
{
    for (int i = blockIdx.x * blockDim.x + threadIdx.x; i < n;
         i += gridDim.x * blockDim.x) {
        const int p = rp[i] + blocksums[i / SCAN_ELEMS];
        rp[i] = p;
        if (cursor) cursor[i] = p;
        if (i == 0) rp[n] = nnz;
    }
}

// Atomic-free scatter: position = row_ptr[row] + slot[e]. CACHED store —
// random 8B writes merge in L2/L3 (~16 stores land per 128B line).
__global__ __launch_bounds__(256) void k_scatter_slot(
    const int* __restrict__ rows, const int* __restrict__ cols,
    const float* __restrict__ vals, const int* __restrict__ row_ptr,
    const int* __restrict__ slot, u64* __restrict__ edges, int nnz)
{
    for (int e = blockIdx.x * blockDim.x + threadIdx.x; e < nnz;
         e += gridDim.x * blockDim.x) {
        const int r = __builtin_nontemporal_load(rows + e);
        const int c = __builtin_nontemporal_load(cols + e);
        const float v = __builtin_nontemporal_load(vals + e);
        const int s = __builtin_nontemporal_load(slot + e);
        const u64 rec = ((u64)(unsigned)__float_as_int(v) << 32)
                      | (u64)(unsigned)c;
        edges[row_ptr[r] + s] = rec;   // cached: let L2 merge
    }
}

// Cursor-atomic scatter (Plan A' fallback), cached store.
__global__ __launch_bounds__(256) void k_scatter_cur(
    const int* __restrict__ rows, const int* __restrict__ cols,
    const float* __restrict__ vals, int* __restrict__ cursor,
    u64* __restrict__ edges, int nnz)
{
    for (int e = blockIdx.x * blockDim.x + threadIdx.x; e < nnz;
         e += gridDim.x * blockDim.x) {
        const int p = atomicAdd(cursor + __builtin_nontemporal_load(rows + e), 1);
        const u64 rec = ((u64)(unsigned)__float_as_int(
                             __builtin_nontemporal_load(vals + e)) << 32)
                      | (u64)(unsigned)__builtin_nontemporal_load(cols + e);
        edges[p] = rec;
    }
}

// ---------------- CSR SpMM: wave per row, lane = dim ----------------
// Edge records enter lane-parallel (1 coalesced 512B VMEM per 64 edges, nt),
// then broadcast to SGPRs via readlane (uniform index -> SGPR lane operand).
// Gather address becomes scalar-base + lane*4; FMA takes the edge value as
// its single SGPR operand. TA sees ~1 instruction per edge (the gather).

__global__ __launch_bounds__(256) void k_spmm(
    const float* __restrict__ x, const int* __restrict__ row_ptr,
    const u64* __restrict__ edges, float* __restrict__ y,
    int n, int rows_per_wave)
{
    const int lane = threadIdx.x & 63;
    const int w = (blockIdx.x * blockDim.x + threadIdx.x) >> 6;
    int r0 = w * rows_per_wave, r1 = r0 + rows_per_wave;
    if (r1 > n) r1 = n;
    for (int r = r0; r < r1; ++r) {
        const int start = __builtin_amdgcn_readfirstlane(row_ptr[r]);
        const int end   = __builtin_amdgcn_readfirstlane(row_ptr[r + 1]);
        float a0 = 0.f, a1 = 0.f, a2 = 0.f, a3 = 0.f;
        for (int j0 = start; j0 < end; j0 += 64) {
            const int nn = (end - j0 < 64) ? (end - j0) : 64;      // uniform
            // lanes >= nn re-load edge j0 (same line, harmless, never consumed)
            const u64 rec = __builtin_nontemporal_load(
                edges + j0 + ((lane < nn) ? lane : 0));
            const int lo = (int)(unsigned)(rec & 0xffffffffu);      // col bits
            const int hi = (int)(unsigned)(rec >> 32);              // val bits
            int k = 0;
            for (; k + 4 <= nn; k += 4) {
                const int   c0 = __builtin_amdgcn_readlane(lo, k + 0);
                const float v0 = __int_as_float(__builtin_amdgcn_readlane(hi, k + 0));
                const int   c1 = __builtin_amdgcn_readlane(lo, k + 1);
                const float v1 = __int_as_float(__builtin_amdgcn_readlane(hi, k + 1));
                const int   c2 = __builtin_amdgcn_readlane(lo, k + 2);
                const float v2 = __int_as_float(__builtin_amdgcn_readlane(hi, k + 2));
                const int   c3 = __builtin_amdgcn_readlane(lo, k + 3);
                const float v3 = __int_as_float(__builtin_amdgcn_readlane(hi, k + 3));
                a0 += v0 * x[(size_t)c0 * DIM + lane];
                a1 += v1 * x[(size_t)c1 * DIM + lane];
                a2 += v2 * x[(size_t)c2 * DIM + lane];
                a3 += v3 * x[(size_t)c3 * DIM + lane];
            }
            for (; k < nn; ++k) {
                const int   c = __builtin_amdgcn_readlane(lo, k);
                const float v = __int_as_float(__builtin_amdgcn_readlane(hi, k));
                a0 += v * x[(size_t)c * DIM + lane];
            }
        }
        // normal (cached) store: this row is next layer's gather table
        y[(size_t)r * DIM + lane] = (a0 + a1) + (a2 + a3);
    }
}

// ---------------- Plan B fallback: per-edge atomic scatter ----------------

__global__ __launch_bounds__(256) void lgcn_atomic(
    const float* __restrict__ x, const float* __restrict__ vals,
    const int* __restrict__ rows, const int* __restrict__ cols,
    float* __restrict__ y, int nnz, int edges_per_wave)
{
    const int lane = threadIdx.x & 63;
    const int wid = (blockIdx.x * blockDim.x + threadIdx.x) >> 6;
    int e0 = wid * edges_per_wave, e1 = e0 + edges_per_wave;
    if (e1 > nnz) e1 = nnz;
    for (int e = e0; e < e1; ++e) {
        const int eu = __builtin_amdgcn_readfirstlane(e);
        const float v = vals[eu];
        const float xv = x[(size_t)cols[eu] * DIM + lane];
        unsafeAtomicAdd(y + (size_t)rows[eu] * DIM + lane, v * xv);
    }
}

// ---------------- host ----------------

static inline size_t align256(size_t x) { return (x + 255) & ~(size_t)255; }

extern "C" void kernel_launch(void* const* d_in, const int* in_sizes, int n_in,
                              void* d_out, int out_size, void* d_ws, size_t ws_size,
                              hipStream_t stream)
{
    const float* user_emb = (const float*)d_in[0];
    const float* item_emb = (const float*)d_in[1];
    const float* vals     = (const float*)d_in[2];
    const int*   rows     = (const int*)d_in[3];
    const int*   cols     = (const int*)d_in[4];
    float*       out      = (float*)d_out;

    const int n   = (in_sizes[0] + in_sizes[1]) / DIM;   // n_nodes
    const int nnz = in_sizes[2];

    const size_t u_bytes  = (size_t)in_sizes[0] * sizeof(float);
    const size_t i_bytes  = (size_t)in_sizes[1] * sizeof(float);
    const size_t x_bytes  = (size_t)n * DIM * sizeof(float);
    const size_t e_bytes  = (size_t)nnz * sizeof(u64);   // interleaved (col,val)
    const size_t s_bytes  = (size_t)nnz * sizeof(int);   // per-edge slot
    const size_t rp_bytes = align256(((size_t)n + 1) * sizeof(int));

    // ws layout
    size_t off = 0;
    float* x_mid  = (float*)((char*)d_ws + off); off += align256(x_bytes);
    u64*   edges  = (u64*)  ((char*)d_ws + off); off += align256(e_bytes);
    int*   row_ptr= (int*)  ((char*)d_ws + off); off += rp_bytes;
    int*   counts = (int*)  ((char*)d_ws + off); off += rp_bytes;
    int*   bsums  = (int*)  ((char*)d_ws + off); off += 256;
    const size_t need_cur = off;            // Plan A' (cursor scatter)
    int*   slot   = (int*)  ((char*)d_ws + off); off += align256(s_bytes);
    const size_t need_full = off;           // Plan A (slot scatter)
    int*   cursor = counts;                 // counts dead after scan1 -> alias

    const int blocks = 2048, threads = 256;
    const int nwaves = blocks * (threads / 64);

    // x0 = concat(user_emb, item_emb) -> x_mid (all plans)
    hipMemcpyAsync(x_mid, user_emb, u_bytes, hipMemcpyDeviceToDevice, stream);
    hipMemcpyAsync((char*)x_mid + u_bytes, item_emb, i_bytes,
                   hipMemcpyDeviceToDevice, stream);

    if (ws_size >= need_cur) {
        // ---- CSR build ----
        const int nb = (n + SCAN_ELEMS - 1) / SCAN_ELEMS;   // 49 <= 64
        const bool full = (ws_size >= need_full);
        hipMemsetAsync(counts, 0, (size_t)n * sizeof(int), stream);
        if (full)
            k_hist_slot<<<blocks, threads, 0, stream>>>(rows, counts, slot, nnz);
        else
            k_hist<<<blocks, threads, 0, stream>>>(rows, counts, nnz);
        k_scan1<<<nb, 256, 0, stream>>>(counts, row_ptr, bsums, n);
        k_scan2<<<1, 64, 0, stream>>>(bsums, nb);
        k_scan3<<<blocks, threads, 0, stream>>>(row_ptr, bsums,
                                                full ? (int*)nullptr : cursor,
                                                n, nnz);
        if (full)
            k_scatter_slot<<<blocks, threads, 0, stream>>>(rows, cols, vals,
                                                           row_ptr, slot, edges, nnz);
        else
            k_scatter_cur<<<blocks, threads, 0, stream>>>(rows, cols, vals,
                                                          cursor, edges, nnz);
        // ---- 3 gather-SpMM layers ----
        const int rpw = (n + nwaves - 1) / nwaves;
        k_spmm<<<blocks, threads, 0, stream>>>(x_mid, row_ptr, edges, out, n, rpw);
        k_spmm<<<blocks, threads, 0, stream>>>(out, row_ptr, edges, x_mid, n, rpw);
        k_spmm<<<blocks, threads, 0, stream>>>(x_mid, row_ptr, edges, out, n, rpw);
    } else {
        // ---- Plan B: atomic scatter (needs only x_mid) ----
        const int epw = (nnz + nwaves - 1) / nwaves;
        hipMemsetAsync(out, 0, x_bytes, stream);
        lgcn_atomic<<<blocks, threads, 0, stream>>>(x_mid, vals, rows, cols, out,
                                                    nnz, epw);
        hipMemsetAsync(x_mid, 0, x_bytes, stream);
        lgcn_atomic<<<blocks, threads, 0, stream>>>(out, vals, rows, cols, x_mid,
                                                    nnz, epw);
        hipMemsetAsync(out, 0, x_bytes, stream);
        lgcn_atomic<<<blocks, threads, 0, stream>>>(x_mid, vals, rows, cols, out,
                                                    nnz, epw);
    }
}

// Round 9
// 570.431 us; speedup vs baseline: 1.4697x; 1.1689x over previous
//
#include <hip/hip_runtime.h>

#define DIM 64

// ---------------------------------------------------------------------------
// LightGCN: 3 x (y[row] += val * x[col]) over COO edges (NNZ=3.2M, N=100k).
//
// Round-6 profile: k_hist_slot 132us (3.2M device-scope atomics = fabric RMW,
// 112MB WRITE for 13MB payload); scatter ~128us (random 8B stores). Fix:
// two-level counting sort with ONLY LDS atomics:
//   P1  k_pcount: per-block LDS hist over 98 row-buckets (1024 rows each)
//   P2  scan bcounts[98][1024] (=100,352 = 49*2048, reuses scan stack)
//   P3  k_pscatter: re-read chunk, LDS cursors from scanned bases ->
//       packed_p records partitioned by bucket. Packed 8B record:
//       [63:32]=val, [26:17]=row&1023, [16:0]=col (col<2^17, N=100k).
//       No rows_p array -> tier-1 ws ~78 MB (was 91).
//   H   k_bucket_csr: 1 block/bucket; LDS 1024-bin hist + LDS scan ->
//       row_ptr; in-bucket scatter to final CSR (strips row bits).
// Then 3 x SpMM wave-per-row (unchanged): 64 edge recs lane-parallel + nt,
// readlane broadcast -> scalar gather base, 256B gather/edge, one 256B
// store/row.
// Tiers by ws_size: radix (~78MB) -> hist_slot (~66MB, measured r6 667us) ->
// cursor (~52MB) -> per-edge atomic (~26MB).
// ---------------------------------------------------------------------------

#define SCAN_ELEMS 2048      // elements per scan block (256 thr x 8)
#define NPB 1024             // partition blocks (P1/P3)
#define BUCKET_SHIFT 10      // 1024 rows per bucket

typedef unsigned long long u64;

// ---------------- radix build: P1 partition count ----------------

__global__ __launch_bounds__(256) void k_pcount(const int* __restrict__ rows,
                                                int* __restrict__ bcounts,
                                                int nnz, int nb, int epb)
{
    __shared__ int h[128];
    const int b = blockIdx.x;
    for (int i = threadIdx.x; i < nb; i += 256) h[i] = 0;
    __syncthreads();
    const int e0 = b * epb;
    const int e1 = (e0 + epb < nnz) ? e0 + epb : nnz;
    for (int e = e0 + threadIdx.x; e < e1; e += 256)
        atomicAdd(&h[__builtin_nontemporal_load(rows + e) >> BUCKET_SHIFT], 1);
    __syncthreads();
    for (int k = threadIdx.x; k < nb; k += 256)
        bcounts[k * NPB + b] = h[k];
}

// ---------------- scan stack (measured, reused) ----------------

__global__ __launch_bounds__(256) void k_scan1(const int* __restrict__ counts,
                                               int* __restrict__ rp,
                                               int* __restrict__ blocksums, int n)
{
    __shared__ int lds[256];
    const int t = threadIdx.x, b = blockIdx.x;
    const int base = b * SCAN_ELEMS + t * 8;
    int v[8], s = 0;
#pragma unroll
    for (int k = 0; k < 8; ++k) {
        const int idx = base + k;
        v[k] = (idx < n) ? counts[idx] : 0;
        s += v[k];
    }
    lds[t] = s;
    __syncthreads();
    for (int off = 1; off < 256; off <<= 1) {
        const int val = (t >= off) ? lds[t - off] : 0;
        __syncthreads();
        lds[t] += val;
        __syncthreads();
    }
    const int incl = lds[t];
    if (t == 255) blocksums[b] = incl;
    int run = incl - s;
#pragma unroll
    for (int k = 0; k < 8; ++k) {
        const int idx = base + k;
        if (idx < n) rp[idx] = run;
        run += v[k];
    }
}

__global__ void k_scan2(int* __restrict__ blocksums, int nb)
{
    const int lane = threadIdx.x;   // 64 threads = 1 wave
    const int v = (lane < nb) ? blocksums[lane] : 0;
    int incl = v;
    for (int off = 1; off < 64; off <<= 1) {
        const int t = __shfl_up(incl, off);
        if (lane >= off) incl += t;
    }
    if (lane < nb) blocksums[lane] = incl - v;
}

__global__ __launch_bounds__(256) void k_scan3(int* __restrict__ rp,
                                               const int* __restrict__ blocksums,
                                               int* __restrict__ cursor,  // may be null
                                               int n, int nnz)
{
    for (int i = blockIdx.x * blockDim.x + threadIdx.x; i < n;
         i += gridDim.x * blockDim.x) {
        const int p = rp[i] + blocksums[i / SCAN_ELEMS];
        rp[i] = p;
        if (cursor) cursor[i] = p;
        if (i == 0) rp[n] = nnz;
    }
}

// ---------------- radix build: P3 partition scatter ----------------
// packed record: [63:32]=val bits, [26:17]=row&1023, [16:0]=col

__global__ __launch_bounds__(256) void k_pscatter(
    const int* __restrict__ rows, const int* __restrict__ cols,
    const float* __restrict__ vals, const int* __restrict__ scan_b,
    u64* __restrict__ packed_p, int nnz, int nb, int epb)
{
    __shared__ int cur[128];
    const int b = blockIdx.x;
    for (int k = threadIdx.x; k < nb; k += 256) cur[k] = scan_b[k * NPB + b];
    __syncthreads();
    const int e0 = b * epb;
    const int e1 = (e0 + epb < nnz) ? e0 + epb : nnz;
    for (int e = e0 + threadIdx.x; e < e1; e += 256) {
        const int r = __builtin_nontemporal_load(rows + e);
        const int c = __builtin_nontemporal_load(cols + e);
        const float v = __builtin_nontemporal_load(vals + e);
        const int p = atomicAdd(&cur[r >> BUCKET_SHIFT], 1);   // LDS atomic
        packed_p[p] = ((u64)(unsigned)__float_as_int(v) << 32)
                    | ((u64)(unsigned)(r & 1023) << 17)
                    | (u64)(unsigned)c;
    }
}

// ---------------- radix build: H per-bucket CSR finalize ----------------

__global__ __launch_bounds__(256) void k_bucket_csr(
    const u64* __restrict__ packed_p, const int* __restrict__ scan_b,
    int* __restrict__ row_ptr, u64* __restrict__ edges,
    int n, int nnz, int nb)
{
    __shared__ int hist[1024];
    __shared__ int wsum[256];
    const int kb = blockIdx.x;
    const int t = threadIdx.x;
    const int bstart = scan_b[kb * NPB];
    const int bend = (kb + 1 < nb) ? scan_b[(kb + 1) * NPB] : nnz;
    for (int i = t; i < 1024; i += 256) hist[i] = 0;
    __syncthreads();
    // pass 1: in-bucket histogram (LDS atomics)
    for (int e = bstart + t; e < bend; e += 256)
        atomicAdd(&hist[(int)((packed_p[e] >> 17) & 1023)], 1);
    __syncthreads();
    // block exclusive scan over 1024 bins, 4 per thread
    const int v0 = hist[4 * t + 0], v1 = hist[4 * t + 1];
    const int v2 = hist[4 * t + 2], v3 = hist[4 * t + 3];
    const int s = v0 + v1 + v2 + v3;
    wsum[t] = s;
    __syncthreads();
    for (int off = 1; off < 256; off <<= 1) {
        const int val = (t >= off) ? wsum[t - off] : 0;
        __syncthreads();
        wsum[t] += val;
        __syncthreads();
    }
    const int run = wsum[t] - s;
    hist[4 * t + 0] = run;                 // overwrite own slots with excl prefix
    hist[4 * t + 1] = run + v0;
    hist[4 * t + 2] = run + v0 + v1;
    hist[4 * t + 3] = run + v0 + v1 + v2;
    __syncthreads();
    // row_ptr for this bucket
    const int gbase = kb << BUCKET_SHIFT;
    for (int i = t; i < 1024; i += 256) {
        const int g = gbase + i;
        if (g < n) row_ptr[g] = bstart + hist[i];
    }
    if (kb == 0 && t == 0) row_ptr[n] = nnz;
    __syncthreads();
    // pass 2: in-bucket scatter to final CSR position (hist now = cursors).
    // Final record: [63:32]=val, [31:0]=col (row bits stripped).
    for (int e = bstart + t; e < bend; e += 256) {
        const u64 rec = packed_p[e];
        const int r = (int)((rec >> 17) & 1023);
        const int p = bstart + atomicAdd(&hist[r], 1);   // LDS atomic
        edges[p] = (rec & 0xFFFFFFFF00000000ULL) | (rec & 0x1FFFFULL);
    }
}

// ---------------- tier-2 build: hist_slot (measured r6) ----------------

__global__ __launch_bounds__(256) void k_hist_slot(const int* __restrict__ rows,
                                                   int* __restrict__ counts,
                                                   int* __restrict__ slot, int nnz)
{
    for (int e = blockIdx.x * blockDim.x + threadIdx.x; e < nnz;
         e += gridDim.x * blockDim.x) {
        const int r = __builtin_nontemporal_load(rows + e);
        slot[e] = atomicAdd(counts + r, 1);
    }
}

__global__ __launch_bounds__(256) void k_hist(const int* __restrict__ rows,
                                              int* __restrict__ counts, int nnz)
{
    for (int e = blockIdx.x * blockDim.x + threadIdx.x; e < nnz;
         e += gridDim.x * blockDim.x)
        atomicAdd(counts + __builtin_nontemporal_load(rows + e), 1);
}

__global__ __launch_bounds__(256) void k_scatter_slot(
    const int* __restrict__ rows, const int* __restrict__ cols,
    const float* __restrict__ vals, const int* __restrict__ row_ptr,
    const int* __restrict__ slot, u64* __restrict__ edges, int nnz)
{
    for (int e = blockIdx.x * blockDim.x + threadIdx.x; e < nnz;
         e += gridDim.x * blockDim.x) {
        const int r = __builtin_nontemporal_load(rows + e);
        const int c = __builtin_nontemporal_load(cols + e);
        const float v = __builtin_nontemporal_load(vals + e);
        const int s = __builtin_nontemporal_load(slot + e);
        const u64 rec = ((u64)(unsigned)__float_as_int(v) << 32)
                      | (u64)(unsigned)c;
        edges[row_ptr[r] + s] = rec;
    }
}

__global__ __launch_bounds__(256) void k_scatter_cur(
    const int* __restrict__ rows, const int* __restrict__ cols,
    const float* __restrict__ vals, int* __restrict__ cursor,
    u64* __restrict__ edges, int nnz)
{
    for (int e = blockIdx.x * blockDim.x + threadIdx.x; e < nnz;
         e += gridDim.x * blockDim.x) {
        const int p = atomicAdd(cursor + __builtin_nontemporal_load(rows + e), 1);
        const u64 rec = ((u64)(unsigned)__float_as_int(
                             __builtin_nontemporal_load(vals + e)) << 32)
                      | (u64)(unsigned)__builtin_nontemporal_load(cols + e);
        edges[p] = rec;
    }
}

// ---------------- CSR SpMM: wave per row, lane = dim (unchanged) ----------

__global__ __launch_bounds__(256) void k_spmm(
    const float* __restrict__ x, const int* __restrict__ row_ptr,
    const u64* __restrict__ edges, float* __restrict__ y,
    int n, int rows_per_wave)
{
    const int lane = threadIdx.x & 63;
    const int w = (blockIdx.x * blockDim.x + threadIdx.x) >> 6;
    int r0 = w * rows_per_wave, r1 = r0 + rows_per_wave;
    if (r1 > n) r1 = n;
    for (int r = r0; r < r1; ++r) {
        const int start = __builtin_amdgcn_readfirstlane(row_ptr[r]);
        const int end   = __builtin_amdgcn_readfirstlane(row_ptr[r + 1]);
        float a0 = 0.f, a1 = 0.f, a2 = 0.f, a3 = 0.f;
        for (int j0 = start; j0 < end; j0 += 64) {
            const int nn = (end - j0 < 64) ? (end - j0) : 64;      // uniform
            const u64 rec = __builtin_nontemporal_load(
                edges + j0 + ((lane < nn) ? lane : 0));
            const int lo = (int)(unsigned)(rec & 0xffffffffu);      // col bits
            const int hi = (int)(unsigned)(rec >> 32);              // val bits
            int k = 0;
            for (; k + 4 <= nn; k += 4) {
                const int   c0 = __builtin_amdgcn_readlane(lo, k + 0);
                const float v0 = __int_as_float(__builtin_amdgcn_readlane(hi, k + 0));
                const int   c1 = __builtin_amdgcn_readlane(lo, k + 1);
                const float v1 = __int_as_float(__builtin_amdgcn_readlane(hi, k + 1));
                const int   c2 = __builtin_amdgcn_readlane(lo, k + 2);
                const float v2 = __int_as_float(__builtin_amdgcn_readlane(hi, k + 2));
                const int   c3 = __builtin_amdgcn_readlane(lo, k + 3);
                const float v3 = __int_as_float(__builtin_amdgcn_readlane(hi, k + 3));
                a0 += v0 * x[(size_t)c0 * DIM + lane];
                a1 += v1 * x[(size_t)c1 * DIM + lane];
                a2 += v2 * x[(size_t)c2 * DIM + lane];
                a3 += v3 * x[(size_t)c3 * DIM + lane];
            }
            for (; k < nn; ++k) {
                const int   c = __builtin_amdgcn_readlane(lo, k);
                const float v = __int_as_float(__builtin_amdgcn_readlane(hi, k));
                a0 += v * x[(size_t)c * DIM + lane];
            }
        }
        y[(size_t)r * DIM + lane] = (a0 + a1) + (a2 + a3);
    }
}

// ---------------- tier-4: per-edge atomic scatter ----------------

__global__ __launch_bounds__(256) void lgcn_atomic(
    const float* __restrict__ x, const float* __restrict__ vals,
    const int* __restrict__ rows, const int* __restrict__ cols,
    float* __restrict__ y, int nnz, int edges_per_wave)
{
    const int lane = threadIdx.x & 63;
    const int wid = (blockIdx.x * blockDim.x + threadIdx.x) >> 6;
    int e0 = wid * edges_per_wave, e1 = e0 + edges_per_wave;
    if (e1 > nnz) e1 = nnz;
    for (int e = e0; e < e1; ++e) {
        const int eu = __builtin_amdgcn_readfirstlane(e);
        const float v = vals[eu];
        const float xv = x[(size_t)cols[eu] * DIM + lane];
        unsafeAtomicAdd(y + (size_t)rows[eu] * DIM + lane, v * xv);
    }
}

// ---------------- host ----------------

static inline size_t align256(size_t x) { return (x + 255) & ~(size_t)255; }

extern "C" void kernel_launch(void* const* d_in, const int* in_sizes, int n_in,
                              void* d_out, int out_size, void* d_ws, size_t ws_size,
                              hipStream_t stream)
{
    const float* user_emb = (const float*)d_in[0];
    const float* item_emb = (const float*)d_in[1];
    const float* vals     = (const float*)d_in[2];
    const int*   rows     = (const int*)d_in[3];
    const int*   cols     = (const int*)d_in[4];
    float*       out      = (float*)d_out;

    const int n   = (in_sizes[0] + in_sizes[1]) / DIM;   // n_nodes
    const int nnz = in_sizes[2];

    const size_t u_bytes  = (size_t)in_sizes[0] * sizeof(float);
    const size_t i_bytes  = (size_t)in_sizes[1] * sizeof(float);
    const size_t x_bytes  = (size_t)n * DIM * sizeof(float);
    const size_t e_bytes  = (size_t)nnz * sizeof(u64);
    const size_t rp_bytes = align256(((size_t)n + 1) * sizeof(int));

    const int nb  = (n + (1 << BUCKET_SHIFT) - 1) >> BUCKET_SHIFT;  // 98
    const int n2  = nb * NPB;                                       // 100,352
    const int epb = (nnz + NPB - 1) / NPB;                          // 3125
    const size_t b_bytes = align256(((size_t)n2 + 256) * sizeof(int));

    const int blocks = 2048, threads = 256;
    const int nwaves = blocks * (threads / 64);

    // common prefix layout: x_mid, edges, row_ptr
    size_t off = 0;
    float* x_mid  = (float*)((char*)d_ws + off); off += align256(x_bytes);
    u64*   edges  = (u64*)  ((char*)d_ws + off); off += align256(e_bytes);
    int*   row_ptr= (int*)  ((char*)d_ws + off); off += rp_bytes;

    // tier-1 (radix) layout — packed records, no rows_p (~78 MB total)
    size_t roff = off;
    int*   bcounts = (int*)((char*)d_ws + roff); roff += b_bytes;
    int*   scan_b  = (int*)((char*)d_ws + roff); roff += b_bytes;
    int*   bsums_r = (int*)((char*)d_ws + roff); roff += 256;
    u64*   packed_p= (u64*)((char*)d_ws + roff); roff += align256(e_bytes);
    const size_t need_radix = roff;

    // tier-2/3 layout (shares prefix)
    size_t hoff = off;
    int*   counts = (int*)((char*)d_ws + hoff); hoff += rp_bytes;
    int*   bsums  = (int*)((char*)d_ws + hoff); hoff += 256;
    const size_t need_cur = hoff;
    int*   slot   = (int*)((char*)d_ws + hoff); hoff += align256((size_t)nnz * sizeof(int));
    const size_t need_full = hoff;
    int*   cursor = counts;

    // x0 = concat(user_emb, item_emb) -> x_mid (all tiers)
    hipMemcpyAsync(x_mid, user_emb, u_bytes, hipMemcpyDeviceToDevice, stream);
    hipMemcpyAsync((char*)x_mid + u_bytes, item_emb, i_bytes,
                   hipMemcpyDeviceToDevice, stream);

    const int rpw = (n + nwaves - 1) / nwaves;

    if (ws_size >= need_radix) {
        // ---- tier 1: LDS-atomic counting-sort build ----
        const int nb2 = (n2 + SCAN_ELEMS - 1) / SCAN_ELEMS;   // 49 <= 64
        k_pcount<<<NPB, threads, 0, stream>>>(rows, bcounts, nnz, nb, epb);
        k_scan1<<<nb2, 256, 0, stream>>>(bcounts, scan_b, bsums_r, n2);
        k_scan2<<<1, 64, 0, stream>>>(bsums_r, nb2);
        k_scan3<<<blocks, threads, 0, stream>>>(scan_b, bsums_r, (int*)nullptr,
                                                n2, nnz);
        k_pscatter<<<NPB, threads, 0, stream>>>(rows, cols, vals, scan_b,
                                                packed_p, nnz, nb, epb);
        k_bucket_csr<<<nb, threads, 0, stream>>>(packed_p, scan_b, row_ptr,
                                                 edges, n, nnz, nb);
        k_spmm<<<blocks, threads, 0, stream>>>(x_mid, row_ptr, edges, out, n, rpw);
        k_spmm<<<blocks, threads, 0, stream>>>(out, row_ptr, edges, x_mid, n, rpw);
        k_spmm<<<blocks, threads, 0, stream>>>(x_mid, row_ptr, edges, out, n, rpw);
    } else if (ws_size >= need_cur) {
        // ---- tier 2/3: fabric-atomic build (measured r6: 667us total) ----
        const int nbs = (n + SCAN_ELEMS - 1) / SCAN_ELEMS;    // 49
        const bool full = (ws_size >= need_full);
        hipMemsetAsync(counts, 0, (size_t)n * sizeof(int), stream);
        if (full)
            k_hist_slot<<<blocks, threads, 0, stream>>>(rows, counts, slot, nnz);
        else
            k_hist<<<blocks, threads, 0, stream>>>(rows, counts, nnz);
        k_scan1<<<nbs, 256, 0, stream>>>(counts, row_ptr, bsums, n);
        k_scan2<<<1, 64, 0, stream>>>(bsums, nbs);
        k_scan3<<<blocks, threads, 0, stream>>>(row_ptr, bsums,
                                                full ? (int*)nullptr : cursor,
                                                n, nnz);
        if (full)
            k_scatter_slot<<<blocks, threads, 0, stream>>>(rows, cols, vals,
                                                           row_ptr, slot, edges, nnz);
        else
            k_scatter_cur<<<blocks, threads, 0, stream>>>(rows, cols, vals,
                                                          cursor, edges, nnz);
        k_spmm<<<blocks, threads, 0, stream>>>(x_mid, row_ptr, edges, out, n, rpw);
        k_spmm<<<blocks, threads, 0, stream>>>(out, row_ptr, edges, x_mid, n, rpw);
        k_spmm<<<blocks, threads, 0, stream>>>(x_mid, row_ptr, edges, out, n, rpw);
    } else {
        // ---- tier 4: per-edge atomic ----
        const int epw = (nnz + nwaves - 1) / nwaves;
        hipMemsetAsync(out, 0, x_bytes, stream);
        lgcn_atomic<<<blocks, threads, 0, stream>>>(x_mid, vals, rows, cols, out,
                                                    nnz, epw);
        hipMemsetAsync(x_mid, 0, x_bytes, stream);
        lgcn_atomic<<<blocks, threads, 0, stream>>>(out, vals, rows, cols, x_mid,
                                                    nnz, epw);
        hipMemsetAsync(out, 0, x_bytes, stream);
        lgcn_atomic<<<blocks, threads, 0, stream>>>(x_mid, vals, rows, cols, out,
                                                    nnz, epw);
    }
}